// Round 9
// baseline (186.145 us; speedup 1.0000x reference)
//
#include <hip/hip_runtime.h>
#include <hip/hip_bf16.h>

// ============================================================================
// B=512, M=40, D=64. Three bilinear layers (200 outputs each):
//   out[o,d] = relu(bias[o] + sum_c W[o,c]*U[c,d]), U[(m,n),d] = x[m,d]*h[n,d]
// Per b: GEMM C[208,64] = W[208,K] x U[K,64] bf16, K=1600/4000/4000.
// R9 = R5 geometry (block = 2 batches, grid 256 = 1/CU, 8 waves = 4 gm x 2 wn,
// shared U-build in LDS with XOR position perm, frag-contiguous W) PLUS
// register-prefetched B-fragments: phase s does {prefetch bv(s+1) from slab
// (s+1)&3 | MFMAs on bv(s) ALREADY IN REGS | build(s+2)->slab (s+2)&3 | bar}.
// MFMAs have no same-phase LDS dependency -> LDS pipe overlaps matrix pipe
// instead of serializing before it (the R5 1500-cyc/kstep stall).
// Slab safety (4 slabs, 1-kstep phases): phase s reads (s+1)&3, writes
// (s+2)&3 - always disjoint; a slab is rewritten 3 phases after its read.
// ============================================================================

typedef float f32x4 __attribute__((ext_vector_type(4)));
typedef short bf16x8 __attribute__((ext_vector_type(8)));
typedef unsigned int uint;

#define XS_STR 44     // bf16; 88B rows
#define HS_STR 108    // bf16; 216B rows

struct LDSState {
    __hip_bfloat16 xs[2][64][XS_STR];     // [bb][d][m]         11264 B
    __hip_bfloat16 hs[2][2][64][HS_STR];  // [pp][bb][d][n]     55296 B
    uint U[4][2][64][16];                 // [slab][bb][d][pos] 32768 B
};

static __device__ __forceinline__ float bflo(uint u) {
    uint v = u << 16; return __builtin_bit_cast(float, v);
}
static __device__ __forceinline__ float bfhi(uint u) {
    uint v = u & 0xffff0000u; return __builtin_bit_cast(float, v);
}
static __device__ __forceinline__ uint pk_bf16(float a, float b) {
    uint r; asm("v_cvt_pk_bf16_f32 %0, %1, %2" : "=v"(r) : "v"(a), "v"(b));
    return r;
}

#define PHASE_BAR() do {                                   \
    asm volatile("s_waitcnt lgkmcnt(0)" ::: "memory");     \
    __builtin_amdgcn_sched_barrier(0);                     \
    __builtin_amdgcn_s_barrier();                          \
    __builtin_amdgcn_sched_barrier(0);                     \
} while (0)

template<int DIV, int NK, int HASH, int ROWLO, int ROWOFF, int HSTR, int A>
__device__ __forceinline__ void layer_core(
    LDSState* L, const bf16x8* __restrict__ wpk, const float* __restrict__ bias,
    const __hip_bfloat16* __restrict__ h0, const __hip_bfloat16* __restrict__ h1,
    int dstpp, float* outb0, float* outb1, int tid, int mt0)
{
    const int lane = tid & 63;
    const int wv = tid >> 6, wn = wv & 1;
    const int q = lane >> 4, lr = lane & 15, d = lane;

    // consume read bases (R5-verified perm)
    const int hdr = (lr >> 1) & 7;
    const uint* ub  = &L->U[0][0][0][0] + wn * 1024;
    const uint* roA = ub + (lr * 16 + 2 * ((2 * q) ^ hdr));
    const uint* roB = ub + (lr * 16 + 2 * ((2 * q + 1) ^ hdr));

    // build write base: wave wv owns k-slots 4wv..4wv+3 (uints 2wv,2wv+1)
    const int hdw = (d >> 1) & 7;
    uint* wb = &L->U[0][0][d][0] + 2 * (wv ^ hdw);

    const __hip_bfloat16* xb0 = &L->xs[0][d][0];
    const __hip_bfloat16* xb1 = &L->xs[1][d][0];
    const __hip_bfloat16* hb0 = h0 + d * HSTR;
    const __hip_bfloat16* hb1 = h1 + d * HSTR;

    f32x4 acc[A][4];
    #pragma unroll
    for (int mi = 0; mi < A; ++mi)
        #pragma unroll
        for (int nj = 0; nj < 4; ++nj)
            acc[mi][nj] = {0.f, 0.f, 0.f, 0.f};

    // build state machine: kstep bk covers slots c0 = 32*bk + 4*wv .. +3
    int bm = (4 * wv) / DIV;
    int bn = (4 * wv) % DIV;
    int bk = 0;
    auto build = [&]() {
        if (bk < NK) {
            const int slab_dw = (bk & 3) * 2048;
            float xf0 = __bfloat162float(xb0[bm]);
            float xf1 = __bfloat162float(xb1[bm]);
            uint2 ha = *(const uint2*)(hb0 + bn);
            uint2 hc = *(const uint2*)(hb1 + bn);
            uint2 w0, w1;
            w0.x = pk_bf16(xf0 * bflo(ha.x), xf0 * bfhi(ha.x));
            w0.y = pk_bf16(xf0 * bflo(ha.y), xf0 * bfhi(ha.y));
            w1.x = pk_bf16(xf1 * bflo(hc.x), xf1 * bfhi(hc.x));
            w1.y = pk_bf16(xf1 * bflo(hc.y), xf1 * bfhi(hc.y));
            *(uint2*)(wb + slab_dw)        = w0;
            *(uint2*)(wb + slab_dw + 1024) = w1;
            bn += 32;
            if (bn >= DIV) { bn -= DIV; ++bm; }
            ++bk;
        }
    };

    // prefetch B-frags for kstep s1 into regs (slab (s1)&3 is barrier-ready)
    auto prefetch_bv = [&](int s1, bf16x8* bv) {
        const int slab_dw = (s1 & 3) * 2048;
        #pragma unroll
        for (int nj = 0; nj < 4; ++nj) {
            union { uint2 u2[2]; bf16x8 v; } t;
            t.u2[0] = *(const uint2*)(roA + slab_dw + nj * 256);
            t.u2[1] = *(const uint2*)(roB + slab_dw + nj * 256);
            bv[nj] = t.v;
        }
    };

    auto consume_regs = [&](bf16x8* f, bf16x8* bv) {
        #pragma unroll
        for (int mi = 0; mi < A; ++mi)
            #pragma unroll
            for (int nj = 0; nj < 4; ++nj)
                acc[mi][nj] = __builtin_amdgcn_mfma_f32_16x16x32_bf16(
                    f[mi], bv[nj], acc[mi][nj], 0, 0, 0);
    };

    const bf16x8* pw = wpk + (size_t)mt0 * NK * 64 + lane;
    auto loadf = [&](bf16x8* f, int s) {
        if (s < NK) {
            #pragma unroll
            for (int mi = 0; mi < A; ++mi)
                f[mi] = pw[(size_t)mi * NK * 64 + (size_t)s * 64];
        }
    };

    bf16x8 fC[A], fN[A], bvC[4], bvN[4];
    loadf(fC, 0); loadf(fN, 1);
    build(); build();            // ksteps 0,1 -> slabs 0,1
    __syncthreads();
    prefetch_bv(0, bvC);         // kstep 0 frags -> regs

    #pragma unroll 1
    for (int s = 0; s + 2 <= NK; s += 2) {
        // phase s: reads slab (s+1)&3, computes kstep s, builds slab (s+2)&3
        prefetch_bv(s + 1, bvN);
        consume_regs(fC, bvC);
        loadf(fC, s + 2);
        build();                 // bk = s+2
        PHASE_BAR();
        // phase s+1: reads slab (s+2)&3, computes kstep s+1, builds (s+3)&3
        if (s + 2 < NK) prefetch_bv(s + 2, bvC);
        consume_regs(fN, bvN);
        loadf(fN, s + 3);
        build();                 // bk = s+3
        PHASE_BAR();
    }
    if (NK & 1) consume_regs(fC, bvC);   // kstep NK-1 (even index)

    // epilogue: C/D layout row = 4q+reg, col = lr (m89-verified)
    float* outp = wn ? outb1 : outb0;
    #pragma unroll
    for (int mi = 0; mi < A; ++mi) {
        const int mt = mt0 + mi;
        #pragma unroll
        for (int reg = 0; reg < 4; ++reg) {
            const int o = 16 * mt + 4 * q + reg;
            if (o < 200) {
                const float bs = bias[o];
                float r0 = fmaxf(acc[mi][0][reg] + bs, 0.f);
                float r1 = fmaxf(acc[mi][1][reg] + bs, 0.f);
                float r2 = fmaxf(acc[mi][2][reg] + bs, 0.f);
                float r3 = fmaxf(acc[mi][3][reg] + bs, 0.f);
                if (HASH && o < 100) {
                    L->hs[dstpp][wn][ 0 + lr][o] = __float2bfloat16(r0);
                    L->hs[dstpp][wn][16 + lr][o] = __float2bfloat16(r1);
                    L->hs[dstpp][wn][32 + lr][o] = __float2bfloat16(r2);
                    L->hs[dstpp][wn][48 + lr][o] = __float2bfloat16(r3);
                }
                if (o >= ROWLO) {
                    float sv = (r0 + r1) + (r2 + r3);
                    sv += __shfl_xor(sv, 1, 64);
                    sv += __shfl_xor(sv, 2, 64);
                    sv += __shfl_xor(sv, 4, 64);
                    sv += __shfl_xor(sv, 8, 64);
                    if (lr == 0) outp[ROWOFF + (o - ROWLO)] = sv;
                }
            }
        }
    }
    __syncthreads();
}

template<int A>
__device__ __forceinline__ void run_layers(
    LDSState* L, const bf16x8* w1p, const bf16x8* w2p, const bf16x8* w3p,
    const float* b1, const float* b2, const float* b3,
    float* outb0, float* outb1, int tid, int mt0)
{
    layer_core< 40,  50, 1, 100,   0, XS_STR, A>(L, w1p, b1,
        &L->xs[0][0][0], &L->xs[1][0][0], 0, outb0, outb1, tid, mt0);
    layer_core<100, 125, 1, 100, 100, HS_STR, A>(L, w2p, b2,
        &L->hs[0][0][0][0], &L->hs[0][1][0][0], 1, outb0, outb1, tid, mt0);
    layer_core<100, 125, 0,   0, 200, HS_STR, A>(L, w3p, b3,
        &L->hs[1][0][0][0], &L->hs[1][1][0][0], 0, outb0, outb1, tid, mt0);
}

__global__ __launch_bounds__(512, 2)
void fused_mfma(const float* __restrict__ x,
                const bf16x8* __restrict__ wpk,
                const float* __restrict__ b1, const float* __restrict__ b2,
                const float* __restrict__ b3, float* __restrict__ out) {
    __shared__ LDSState L;
    const int tid = threadIdx.x;
    const int bi  = blockIdx.x;

    // stage x (2 b's), fp32 -> bf16, transposed to [d][m]
    const float* xg = x + (size_t)(2 * bi) * 2560;
    for (int i = tid; i < 5120; i += 512) {
        int bb = (i >= 2560) ? 1 : 0;
        int r  = i - bb * 2560;
        L.xs[bb][r & 63][r >> 6] = __float2bfloat16(xg[(size_t)bb * 2560 + r]);
    }
    __syncthreads();

    float* outb0 = out + (size_t)(2 * bi + 0) * 400;
    float* outb1 = out + (size_t)(2 * bi + 1) * 400;

    const bf16x8* w1p = wpk;              // 13*50*64  = 41600 frags
    const bf16x8* w2p = wpk + 41600;      // 13*125*64 = 104000
    const bf16x8* w3p = wpk + 145600;

    const int wm = tid >> 7;              // wave-pair id 0..3
    if (wm == 0)
        run_layers<4>(&L, w1p, w2p, w3p, b1, b2, b3, outb0, outb1, tid, 0);
    else
        run_layers<3>(&L, w1p, w2p, w3p, b1, b2, b3, outb0, outb1, tid,
                      3 * wm + 1);
}

// ---------------------------------------------------------------------------
// Prepass: repack W fp32 -> bf16 frag-contiguous. Element c = one lane's
// bf16x8: c = layerbase + (mt*NK + s)*64 + lane, holding
// W[16*mt + (lane&15), 32*s + 8*(lane>>4) .. +8]  (rows >= 200 zero).
// ---------------------------------------------------------------------------
__global__ void convert_pack(const float* __restrict__ w1, const float* __restrict__ w2,
                             const float* __restrict__ w3, uint4* __restrict__ outp) {
    int c = blockIdx.x * 256 + threadIdx.x;
    if (c >= 249600) return;
    const float* src; int K, base;
    if (c < 41600)       { src = w1; K = 1600; base = c; }
    else if (c < 145600) { src = w2; K = 4000; base = c - 41600; }
    else                 { src = w3; K = 4000; base = c - 145600; }
    const int NS   = K / 32;
    const int lane = base & 63;
    const int t    = base >> 6;
    const int mt   = t / NS;
    const int s    = t - mt * NS;
    const int row  = 16 * mt + (lane & 15);
    const int k0   = 32 * s + 8 * (lane >> 4);
    uint o[4];
    if (row < 200) {
        const float* p = src + (size_t)row * K + k0;
        #pragma unroll
        for (int j = 0; j < 4; ++j) {
            __hip_bfloat16 lo = __float2bfloat16(p[2 * j]);
            __hip_bfloat16 hi = __float2bfloat16(p[2 * j + 1]);
            o[j] = (uint)__builtin_bit_cast(unsigned short, lo)
                 | ((uint)__builtin_bit_cast(unsigned short, hi) << 16);
        }
    } else {
        #pragma unroll
        for (int j = 0; j < 4; ++j) o[j] = 0u;
    }
    uint4 v; v.x = o[0]; v.y = o[1]; v.z = o[2]; v.w = o[3];
    outp[c] = v;
}

// ---------------------------------------------------------------------------
// Fallback (fp32 VALU kernel) if ws too small.
// ---------------------------------------------------------------------------
__global__ __launch_bounds__(512, 1)
void fused_bilinear_kernel(const float* __restrict__ x,
                           const float* __restrict__ w1, const float* __restrict__ b1,
                           const float* __restrict__ w2, const float* __restrict__ b2,
                           const float* __restrict__ w3, const float* __restrict__ b3,
                           float* __restrict__ out) {
    const int b   = blockIdx.x;
    const int tid = threadIdx.x;
    const int d   = tid & 63;
    const int wv  = tid >> 6;

    __shared__ float xs[40][64];
    __shared__ float hs[100][64];

    const float* xb = x + (size_t)b * 40 * 64;
    for (int i = tid; i < 40 * 64; i += 512) ((float*)xs)[i] = xb[i];
    __syncthreads();

    float xr[40];
    #pragma unroll
    for (int m = 0; m < 40; ++m) xr[m] = xs[m][d];
    float hr[100];
    const int o0 = __builtin_amdgcn_readfirstlane(wv * 25);

    for (int oi = 0; oi < 25; ++oi) {
        const int o = o0 + oi;
        const float* __restrict__ wrow = w1 + (size_t)o * 1600;
        float s = b1[o];
        for (int m = 0; m < 40; ++m) {
            const float* __restrict__ wm = wrow + m * 40;
            float a0 = 0.f, a1 = 0.f, a2 = 0.f, a3 = 0.f;
            #pragma unroll
            for (int n = 0; n < 40; n += 4) {
                a0 = fmaf(wm[n + 0], xr[n + 0], a0);
                a1 = fmaf(wm[n + 1], xr[n + 1], a1);
                a2 = fmaf(wm[n + 2], xr[n + 2], a2);
                a3 = fmaf(wm[n + 3], xr[n + 3], a3);
            }
            s = fmaf(xs[m][d], (a0 + a1) + (a2 + a3), s);
        }
        s = fmaxf(s, 0.f);
        if (o < 100) hs[o][d] = s;
        else {
            float r = s;
            #pragma unroll
            for (int off = 32; off > 0; off >>= 1) r += __shfl_xor(r, off, 64);
            if (d == 0) out[(size_t)b * 400 + (o - 100)] = r;
        }
    }
    __syncthreads();
    #pragma unroll
    for (int n = 0; n < 100; ++n) hr[n] = hs[n][d];
    __syncthreads();

    for (int oi = 0; oi < 25; ++oi) {
        const int o = o0 + oi;
        const float* __restrict__ wrow = w2 + (size_t)o * 4000;
        float s = b2[o];
        for (int m = 0; m < 40; ++m) {
            const float* __restrict__ wm = wrow + m * 100;
            float a0 = 0.f, a1 = 0.f, a2 = 0.f, a3 = 0.f;
            #pragma unroll
            for (int n = 0; n < 100; n += 4) {
                a0 = fmaf(wm[n + 0], hr[n + 0], a0);
                a1 = fmaf(wm[n + 1], hr[n + 1], a1);
                a2 = fmaf(wm[n + 2], hr[n + 2], a2);
                a3 = fmaf(wm[n + 3], hr[n + 3], a3);
            }
            s = fmaf(xs[m][d], (a0 + a1) + (a2 + a3), s);
        }
        s = fmaxf(s, 0.f);
        if (o < 100) hs[o][d] = s;
        else {
            float r = s;
            #pragma unroll
            for (int off = 32; off > 0; off >>= 1) r += __shfl_xor(r, off, 64);
            if (d == 0) out[(size_t)b * 400 + 100 + (o - 100)] = r;
        }
    }
    __syncthreads();
    #pragma unroll
    for (int n = 0; n < 100; ++n) hr[n] = hs[n][d];

    for (int oi = 0; oi < 25; ++oi) {
        const int o = o0 + oi;
        const float* __restrict__ wrow = w3 + (size_t)o * 4000;
        float s = b3[o];
        for (int m = 0; m < 40; ++m) {
            const float* __restrict__ wm = wrow + m * 100;
            float a0 = 0.f, a1 = 0.f, a2 = 0.f, a3 = 0.f;
            #pragma unroll
            for (int n = 0; n < 100; n += 4) {
                a0 = fmaf(wm[n + 0], hr[n + 0], a0);
                a1 = fmaf(wm[n + 1], hr[n + 1], a1);
                a2 = fmaf(wm[n + 2], hr[n + 2], a2);
                a3 = fmaf(wm[n + 3], hr[n + 3], a3);
            }
            s = fmaf(xs[m][d], (a0 + a1) + (a2 + a3), s);
        }
        s = fmaxf(s, 0.f);
        float r = s;
        #pragma unroll
        for (int off = 32; off > 0; off >>= 1) r += __shfl_xor(r, off, 64);
        if (d == 0) out[(size_t)b * 400 + 200 + o] = r;
    }
}

extern "C" void kernel_launch(void* const* d_in, const int* in_sizes, int n_in,
                              void* d_out, int out_size, void* d_ws, size_t ws_size,
                              hipStream_t stream) {
    const float* x  = (const float*)d_in[0];
    const float* w1 = (const float*)d_in[1];
    const float* b1 = (const float*)d_in[2];
    const float* w2 = (const float*)d_in[3];
    const float* b2 = (const float*)d_in[4];
    const float* w3 = (const float*)d_in[5];
    const float* b3 = (const float*)d_in[6];
    float* out = (float*)d_out;

    if (ws_size >= 249600u * 16u) {
        uint4* wp = (uint4*)d_ws;
        convert_pack<<<dim3(975), dim3(256), 0, stream>>>(w1, w2, w3, wp);
        fused_mfma<<<dim3(256), dim3(512), 0, stream>>>(
            x, (const bf16x8*)wp, b1, b2, b3, out);
    } else {
        fused_bilinear_kernel<<<dim3(512), dim3(512), 0, stream>>>(
            x, w1, b1, w2, b2, w3, b3, out);
    }
}